// Round 6
// baseline (261.180 us; speedup 1.0000x reference)
//
#include <hip/hip_runtime.h>
#include <hip/hip_bf16.h>

// B=4, N=M=2048, D=512, H=8, HS=64, OUT=512
// conv_wqkv : W[H][D][HS] fp32 -> Wt[h*64+hs][k] bf16 (q scaled 1/8)
// conv_wp   : W[H][HS][OUT] fp32 -> Wt[out][h*64+hs] bf16
// gemm128<0>: X fp32 [8192,512] x Wt -> Q,K: [B*H][n][64] bf16; V: [B*H][hs][m] bf16 (transposed)
// attn64    : flash attn per (b,h), 64 q-rows/block, gload_lds dbuf pipeline -> MH bf16
// gemm128<1>: MH x Wp_t + bias -> out fp32 [8192,512]
//
// Staging uses global_load_lds (linear LDS dest) with pre-XORed global source column
// (scol = (lane&7)^(lane>>3)), the inverse of swz() -- reads keep swz() unchanged.

typedef __attribute__((ext_vector_type(8))) short short8;
typedef __attribute__((ext_vector_type(4))) float f32x4;

#define MFMA16(a, b, c) __builtin_amdgcn_mfma_f32_16x16x32_bf16(a, b, c, 0, 0, 0)

__device__ __forceinline__ short f2bf(float f) {
  unsigned u = __builtin_bit_cast(unsigned, f);
  u += 0x7FFF + ((u >> 16) & 1);   // RNE
  return (short)(u >> 16);
}

// XOR swizzle for 128B-row LDS tiles (bases must have bits 7-9 clear).
__device__ __forceinline__ unsigned swz(unsigned byte) {
  return byte ^ (((byte >> 7) & 7) << 4);
}

__device__ __forceinline__ void gload16(const void* g, void* l) {
  __builtin_amdgcn_global_load_lds((const __attribute__((address_space(1))) void*)g,
                                   (__attribute__((address_space(3))) void*)l, 16, 0, 0);
}

// ---------------- weight conversion ----------------

__global__ void conv_wqkv(const float* __restrict__ Wq, const float* __restrict__ Wk,
                          const float* __restrict__ Wv,
                          short* __restrict__ Oq, short* __restrict__ Ok,
                          short* __restrict__ Ov) {
  int z = blockIdx.y;
  const float* W = (z == 0) ? Wq : (z == 1) ? Wk : Wv;
  short* O = (z == 0) ? Oq : (z == 1) ? Ok : Ov;
  float scale = (z == 0) ? 0.125f : 1.0f;
  int tid = blockIdx.x * 256 + threadIdx.x;
  int n = tid >> 9, k = tid & 511;
  int h = n >> 6, hs = n & 63;
  O[tid] = f2bf(W[(h * 512 + k) * 64 + hs] * scale);
}

__global__ void conv_wp(const float* __restrict__ W, short* __restrict__ O) {
  int tid = blockIdx.x * 256 + threadIdx.x;
  int n = tid >> 9, k = tid & 511;
  O[tid] = f2bf(W[k * 512 + n]);
}

// ---------------- GEMM: 128x128 tile, BK=64, dbuf, gload_lds B staging ----------------

template <int MODE>
__global__ __launch_bounds__(256) void gemm128(
    const void* __restrict__ A0, const void* __restrict__ A1, const void* __restrict__ A2,
    const short* __restrict__ B0, const short* __restrict__ B1, const short* __restrict__ B2,
    void* __restrict__ O0, void* __restrict__ O1, void* __restrict__ O2,
    const float* __restrict__ bias) {
  __shared__ alignas(16) char lds[65536];  // A bufs @0,@16384; B bufs @32768,@49152
  const int z = blockIdx.z;
  const void* Ap = (z == 0) ? A0 : (z == 1) ? A1 : A2;
  const short* Bp = (z == 0) ? B0 : (z == 1) ? B1 : B2;
  void* Op = (z == 0) ? O0 : (z == 1) ? O1 : O2;

  const int tid = threadIdx.x;
  const int r0 = blockIdx.x * 128;
  const int n0 = blockIdx.y * 128;
  const int wid = tid >> 6, lane = tid & 63, g = lane >> 4, c = lane & 15;
  const int wr = wid >> 1, wc = wid & 1;
  const int rl = lane >> 3, cl = lane & 7, scol = cl ^ rl;  // gload_lds lane geometry
  const int srow = tid >> 3, sc8 = tid & 7;                 // MODE0 A reg staging

  float4 fA[4], fB[4];

  auto LOAD_A = [&](int ks) {   // MODE 0: fp32 -> regs
    const int k0 = ks * 64;
#pragma unroll
    for (int it = 0; it < 4; ++it) {
      int row = srow + 32 * it;
      const float* src = (const float*)Ap + (size_t)(r0 + row) * 512 + k0 + sc8 * 8;
      fA[it] = *(const float4*)(src);
      fB[it] = *(const float4*)(src + 4);
    }
  };
  auto WRITE_A = [&](int buf) {  // MODE 0: convert + swizzled ds_write
    char* Ab = lds + buf * 16384;
#pragma unroll
    for (int it = 0; it < 4; ++it) {
      int row = srow + 32 * it;
      short8 s;
      s[0] = f2bf(fA[it].x); s[1] = f2bf(fA[it].y); s[2] = f2bf(fA[it].z); s[3] = f2bf(fA[it].w);
      s[4] = f2bf(fB[it].x); s[5] = f2bf(fB[it].y); s[6] = f2bf(fB[it].z); s[7] = f2bf(fB[it].w);
      *(short8*)(Ab + swz(row * 128 + sc8 * 16)) = s;
    }
  };
  auto ISSUE_A = [&](int ks, int buf) {  // MODE 1: bf16 direct to LDS
    char* Ab = lds + buf * 16384;
    const int k0 = ks * 64;
#pragma unroll
    for (int i = 0; i < 4; ++i) {
      int ch = wid * 4 + i;
      int row = ch * 8 + rl;
      gload16((const short*)Ap + (size_t)(r0 + row) * 512 + k0 + scol * 8, Ab + ch * 1024);
    }
  };
  auto ISSUE_B = [&](int ks, int buf) {
    char* Bb = lds + 32768 + buf * 16384;
    const int k0 = ks * 64;
#pragma unroll
    for (int i = 0; i < 4; ++i) {
      int ch = wid * 4 + i;
      int row = ch * 8 + rl;
      gload16(Bp + (size_t)(n0 + row) * 512 + k0 + scol * 8, Bb + ch * 1024);
    }
  };

  f32x4 acc[4][4] = {};

  if constexpr (MODE == 0) { LOAD_A(0); WRITE_A(0); } else { ISSUE_A(0, 0); }
  ISSUE_B(0, 0);
  int cur = 0;

  for (int ks = 0; ks < 8; ++ks) {
    __syncthreads();   // drains prev gloads + ds_writes; buf[cur] ready
    if (ks < 7) {
      ISSUE_B(ks + 1, cur ^ 1);
      if constexpr (MODE == 1) ISSUE_A(ks + 1, cur ^ 1);
      else LOAD_A(ks + 1);
    }
    const char* Ab = lds + cur * 16384;
    const char* Bb = lds + 32768 + cur * 16384;

    short8 af[4][2], bf[4][2];
#pragma unroll
    for (int mt = 0; mt < 4; ++mt)
#pragma unroll
      for (int kk = 0; kk < 2; ++kk) {
        int row = wr * 64 + mt * 16 + c;
        af[mt][kk] = *(const short8*)(Ab + swz(row * 128 + (g + 4 * kk) * 16));
      }
#pragma unroll
    for (int nt = 0; nt < 4; ++nt)
#pragma unroll
      for (int kk = 0; kk < 2; ++kk) {
        int nr = wc * 64 + nt * 16 + c;
        bf[nt][kk] = *(const short8*)(Bb + swz(nr * 128 + (g + 4 * kk) * 16));
      }
#pragma unroll
    for (int mt = 0; mt < 4; ++mt)
#pragma unroll
      for (int nt = 0; nt < 4; ++nt) {
        acc[mt][nt] = MFMA16(af[mt][0], bf[nt][0], acc[mt][nt]);
        acc[mt][nt] = MFMA16(af[mt][1], bf[nt][1], acc[mt][nt]);
      }

    if constexpr (MODE == 0) {
      if (ks < 7) WRITE_A(cur ^ 1);
    }
    cur ^= 1;
  }

  if constexpr (MODE == 0) {
    short* Ob = (short*)Op;
    const bool vtrans = (z == 2);
#pragma unroll
    for (int mt = 0; mt < 4; ++mt) {
      int rowb = r0 + wr * 64 + mt * 16 + g * 4;
#pragma unroll
      for (int nt = 0; nt < 4; ++nt) {
        int col = n0 + wc * 64 + nt * 16 + c;
        int hh = col >> 6, hs = col & 63;
#pragma unroll
        for (int r = 0; r < 4; ++r) {
          int row = rowb + r;
          int bb = row >> 11, nn = row & 2047;
          size_t off = vtrans ? ((((size_t)(bb * 8 + hh)) * 64 + hs) * 2048 + nn)
                              : ((((size_t)(bb * 8 + hh)) * 2048 + nn) * 64 + hs);
          Ob[off] = f2bf(acc[mt][nt][r]);
        }
      }
    }
  } else {
    float* Of = (float*)Op;
#pragma unroll
    for (int nt = 0; nt < 4; ++nt) {
      int col = n0 + wc * 64 + nt * 16 + c;
      float bv = bias[col];
#pragma unroll
      for (int mt = 0; mt < 4; ++mt) {
        int rowb = r0 + wr * 64 + mt * 16 + g * 4;
#pragma unroll
        for (int r = 0; r < 4; ++r)
          Of[(size_t)(rowb + r) * 512 + col] = acc[mt][nt][r] + bv;
      }
    }
  }
}

// ---------------- flash attention: gload_lds dbuf K/V, 1 barrier/tile ----------------
// 256 thr = 4 waves, 16 q-rows/wave. LDS 40KB:
//   Kbuf[2] [64 kv][64 d]  @0, @8192      (linear store, swz-equivalent via src perm)
//   Vbuf[2] [64 hs][64 kv] @16384, @24576 (V^T tiles; Vt global layout [bh][hs][m])
//   P per wave [16 q][64 kv] @32768 + wid*2048

__global__ __launch_bounds__(256, 4) void attn64(const short* __restrict__ Qb,
                                                 const short* __restrict__ Kb,
                                                 const short* __restrict__ Vt,
                                                 short* __restrict__ MH) {
  __shared__ alignas(16) char lds[40960];
  // XCD-aware remap: all 32 q-blocks of one (b,h) land on one XCD.
  const int flat = blockIdx.x;
  const int xcd = flat & 7, idx = flat >> 3;
  const int bh = xcd * 4 + (idx >> 5);
  const int qt = idx & 31;
  const int b = bh >> 3, h = bh & 7;

  const int tid = threadIdx.x, wid = tid >> 6, lane = tid & 63, g = lane >> 4, c = lane & 15;
  const short* Qp = Qb + ((size_t)bh * 2048 + qt * 64) * 64;
  const short* Kp = Kb + (size_t)bh * 2048 * 64;
  const short* Vp = Vt + (size_t)bh * 64 * 2048;

  const int rl = lane >> 3, cl = lane & 7, scol = cl ^ rl;

  auto ISSUE_KV = [&](int kvt, int buf) {
    char* Kd = lds + buf * 8192;
    char* Vd = lds + 16384 + buf * 8192;
#pragma unroll
    for (int i = 0; i < 2; ++i) {
      int ch = wid * 2 + i;
      int row = ch * 8 + rl;
      gload16(Kp + ((size_t)kvt * 64 + row) * 64 + scol * 8, Kd + ch * 1024);
      gload16(Vp + (size_t)row * 2048 + kvt * 64 + scol * 8, Vd + ch * 1024);
    }
  };

  short8 qf[2];
#pragma unroll
  for (int kk = 0; kk < 2; ++kk)
    qf[kk] = *(const short8*)(Qp + (wid * 16 + c) * 64 + g * 8 + kk * 32);

  f32x4 o[4] = {};
  float mrow[4], lrow[4];
#pragma unroll
  for (int r = 0; r < 4; ++r) { mrow[r] = -1e30f; lrow[r] = 0.f; }

  const int pbase = 32768 + wid * 2048;

  ISSUE_KV(0, 0);
  int cur = 0;

  for (int kvt = 0; kvt < 32; ++kvt) {
    __syncthreads();   // drains gloads: buf[cur] ready
    if (kvt < 31) ISSUE_KV(kvt + 1, cur ^ 1);
    const char* Kl = lds + cur * 8192;
    const char* Vl = lds + 16384 + cur * 8192;

    // ---- S = Q K^T (16 q-rows x 64 kv) ----
    f32x4 s[4] = {};
#pragma unroll
    for (int t = 0; t < 4; ++t)
#pragma unroll
      for (int kk = 0; kk < 2; ++kk) {
        short8 kf = *(const short8*)(Kl + swz((t * 16 + c) * 128 + (g + 4 * kk) * 16));
        s[t] = MFMA16(qf[kk], kf, s[t]);
      }

    // ---- online softmax (row r at q = g*4+r; kv across 16 lanes x 4 tiles) ----
#pragma unroll
    for (int r = 0; r < 4; ++r) {
      float vm = fmaxf(fmaxf(s[0][r], s[1][r]), fmaxf(s[2][r], s[3][r]));
      vm = fmaxf(vm, __shfl_xor(vm, 1));
      vm = fmaxf(vm, __shfl_xor(vm, 2));
      vm = fmaxf(vm, __shfl_xor(vm, 4));
      vm = fmaxf(vm, __shfl_xor(vm, 8));
      float mn = fmaxf(mrow[r], vm);
      float sc = __expf(mrow[r] - mn);
      float rs = 0.f;
#pragma unroll
      for (int t = 0; t < 4; ++t) {
        float p = __expf(s[t][r] - mn);
        s[t][r] = p;
        rs += p;
      }
      rs += __shfl_xor(rs, 1);
      rs += __shfl_xor(rs, 2);
      rs += __shfl_xor(rs, 4);
      rs += __shfl_xor(rs, 8);
      lrow[r] = lrow[r] * sc + rs;
      mrow[r] = mn;
#pragma unroll
      for (int t = 0; t < 4; ++t) o[t][r] *= sc;
    }

    // ---- P -> per-wave LDS (bf16), then PV ----
#pragma unroll
    for (int t = 0; t < 4; ++t)
#pragma unroll
      for (int r = 0; r < 4; ++r)
        *(short*)(lds + swz(pbase + (g * 4 + r) * 128 + (t * 16 + c) * 2)) = f2bf(s[t][r]);
    asm volatile("s_waitcnt lgkmcnt(0)" ::: "memory");

    short8 pa[2];
#pragma unroll
    for (int half = 0; half < 2; ++half)
      pa[half] = *(const short8*)(lds + swz(pbase + c * 128 + (g + 4 * half) * 16));
#pragma unroll
    for (int t = 0; t < 4; ++t)
#pragma unroll
      for (int half = 0; half < 2; ++half) {
        short8 vf = *(const short8*)(Vl + swz((t * 16 + c) * 128 + (g + 4 * half) * 16));
        o[t] = MFMA16(pa[half], vf, o[t]);
      }

    cur ^= 1;
  }

  // ---- epilogue ----
#pragma unroll
  for (int t = 0; t < 4; ++t)
#pragma unroll
    for (int r = 0; r < 4; ++r) {
      float val = o[t][r] / lrow[r];
      int qrow = qt * 64 + wid * 16 + g * 4 + r;
      int col = h * 64 + t * 16 + c;
      MH[((size_t)b * 2048 + qrow) * 512 + col] = f2bf(val);
    }
}

// ---------------- launcher ----------------

extern "C" void kernel_launch(void* const* d_in, const int* in_sizes, int n_in,
                              void* d_out, int out_size, void* d_ws, size_t ws_size,
                              hipStream_t stream) {
  const float* query = (const float*)d_in[0];
  const float* key = (const float*)d_in[1];
  const float* value = (const float*)d_in[2];
  const float* wq = (const float*)d_in[3];
  const float* wk = (const float*)d_in[4];
  const float* wv = (const float*)d_in[5];
  const float* wp = (const float*)d_in[6];
  const float* bias = (const float*)d_in[7];

  char* ws = (char*)d_ws;
  short* Wq_t = (short*)(ws + 0);
  short* Wk_t = (short*)(ws + 524288);
  short* Wv_t = (short*)(ws + 1048576);
  short* Wp_t = (short*)(ws + 1572864);
  short* Qb = (short*)(ws + 2097152);
  short* Kb = (short*)(ws + 2097152 + 8388608);
  short* Vb = (short*)(ws + 2097152 + 2 * (size_t)8388608);   // Vt[bh][hs][m]
  short* MH = (short*)(ws + 2097152 + 3 * (size_t)8388608);

  conv_wqkv<<<dim3(1024, 3), 256, 0, stream>>>(wq, wk, wv, Wq_t, Wk_t, Wv_t);
  conv_wp<<<1024, 256, 0, stream>>>(wp, Wp_t);
  gemm128<0><<<dim3(64, 4, 3), 256, 0, stream>>>(query, key, value, Wq_t, Wk_t, Wv_t,
                                                 Qb, Kb, Vb, nullptr);
  attn64<<<dim3(1024), 256, 0, stream>>>(Qb, Kb, Vb, MH);
  gemm128<1><<<dim3(64, 4, 1), 256, 0, stream>>>(MH, nullptr, nullptr, Wp_t, nullptr, nullptr,
                                                 d_out, nullptr, nullptr, bias);
}

// Round 10
// 242.926 us; speedup vs baseline: 1.0751x; 1.0751x over previous
//
#include <hip/hip_runtime.h>
#include <hip/hip_bf16.h>

// B=4, N=M=2048, D=512, H=8, HS=64, OUT=512
// convT_qkv : LDS-transpose W[H][D][HS] fp32 -> Wt[h*64+hs][k] bf16 (q scaled 1/8)
// convT_p   : LDS-transpose W[H][HS][OUT] fp32 -> Wt[out][h*64+hs] bf16
// gemmT<0,128>: X fp32 [8192,512] x Wt -> Q,K: [B*H][n][64]; V: [B*H][hs][m] (transposed)
// attn64    : flash attn (UNCHANGED from round 6, passing)
// gemmT<1,64> : MH x Wp_t + bias -> out fp32 [8192,512]

typedef __attribute__((ext_vector_type(8))) short short8;
typedef __attribute__((ext_vector_type(4))) float f32x4;

#define MFMA16(a, b, c) __builtin_amdgcn_mfma_f32_16x16x32_bf16(a, b, c, 0, 0, 0)

__device__ __forceinline__ short f2bf(float f) {
  unsigned u = __builtin_bit_cast(unsigned, f);
  u += 0x7FFF + ((u >> 16) & 1);   // RNE
  return (short)(u >> 16);
}

// XOR swizzle for 128B-row LDS tiles (bases must have bits 7-9 clear).
__device__ __forceinline__ unsigned swz(unsigned byte) {
  return byte ^ (((byte >> 7) & 7) << 4);
}

__device__ __forceinline__ void gload16(const void* g, void* l) {
  __builtin_amdgcn_global_load_lds((const __attribute__((address_space(1))) void*)g,
                                   (__attribute__((address_space(3))) void*)l, 16, 0, 0);
}

// ---------------- weight conversion: coalesced LDS transpose ----------------

__global__ void convT_qkv(const float* __restrict__ Wq, const float* __restrict__ Wk,
                          const float* __restrict__ Wv,
                          short* __restrict__ Oq, short* __restrict__ Ok,
                          short* __restrict__ Ov) {
  __shared__ short t[64][66];
  const int z = blockIdx.y;
  const float* W = (z == 0) ? Wq : (z == 1) ? Wk : Wv;
  short* O = (z == 0) ? Oq : (z == 1) ? Ok : Ov;
  const float scale = (z == 0) ? 0.125f : 1.0f;
  const int h = blockIdx.x >> 3, kb = blockIdx.x & 7;
  const int cl = threadIdx.x & 63, rw = threadIdx.x >> 6;
#pragma unroll
  for (int it = 0; it < 16; ++it) {
    int k = rw + it * 4;
    t[cl][k] = f2bf(W[((size_t)(h * 512) + kb * 64 + k) * 64 + cl] * scale);
  }
  __syncthreads();
#pragma unroll
  for (int it = 0; it < 16; ++it) {
    int hs = rw + it * 4;
    O[((size_t)(h * 64) + hs) * 512 + kb * 64 + cl] = t[hs][cl];
  }
}

__global__ void convT_p(const float* __restrict__ W, short* __restrict__ O) {
  __shared__ short t[64][66];
  const int kb = blockIdx.x & 7, nb = blockIdx.x >> 3;
  const int cl = threadIdx.x & 63, rw = threadIdx.x >> 6;
#pragma unroll
  for (int it = 0; it < 16; ++it) {
    int k = rw + it * 4;
    t[k][cl] = f2bf(W[(size_t)(kb * 64 + k) * 512 + nb * 64 + cl]);
  }
  __syncthreads();
#pragma unroll
  for (int it = 0; it < 16; ++it) {
    int n = rw + it * 4;
    O[(size_t)(nb * 64 + n) * 512 + kb * 64 + cl] = t[cl][n];
  }
}

// ---------------- GEMM: TMx128 tile, BK=64, single-buffer, 2 barriers/k-step ----------------
// MODE 0 (TM=128): A fp32 reg-prefetched+converted; B gload_lds. Epilogue scatter bf16.
// MODE 1 (TM=64) : A+B gload_lds (m97 style). Epilogue fp32 + bias.

template <int MODE, int TM>
__global__ __launch_bounds__(256, 3) void gemmT(
    const void* __restrict__ A0, const void* __restrict__ A1, const void* __restrict__ A2,
    const short* __restrict__ B0, const short* __restrict__ B1, const short* __restrict__ B2,
    void* __restrict__ O0, void* __restrict__ O1, void* __restrict__ O2,
    const float* __restrict__ bias) {
  constexpr int MT = TM / 32;                 // A-frag tiles per wave (wave owns TM/2 rows)
  __shared__ alignas(16) char lds[TM * 128 + 16384];  // A [TM][64] @0, B [128][64] @TM*128
  const int z = blockIdx.z;
  const void* Ap = (z == 0) ? A0 : (z == 1) ? A1 : A2;
  const short* Bp = (z == 0) ? B0 : (z == 1) ? B1 : B2;
  void* Op = (z == 0) ? O0 : (z == 1) ? O1 : O2;

  const int tid = threadIdx.x;
  const int r0 = blockIdx.x * TM;
  const int n0 = blockIdx.y * 128;
  const int wid = tid >> 6, lane = tid & 63, g = lane >> 4, c = lane & 15;
  const int wr = wid >> 1, wc = wid & 1;
  const int rl = lane >> 3, cl = lane & 7, scol = cl ^ rl;  // gload_lds lane geometry
  const int srow = tid >> 3, sc8 = tid & 7;                 // reg-staging geometry

  float4 fA[MT], fB[MT];

  auto LOAD_A = [&](int ks) {   // MODE 0 only: fp32 -> regs (issued during compute)
    const int k0 = ks * 64;
#pragma unroll
    for (int it = 0; it < MT; ++it) {
      int row = srow + 32 * it;
      const float* src = (const float*)Ap + (size_t)(r0 + row) * 512 + k0 + sc8 * 8;
      fA[it] = *(const float4*)(src);
      fB[it] = *(const float4*)(src + 4);
    }
  };
  auto WRITE_A = [&]() {        // MODE 0: convert + swizzled ds_write
#pragma unroll
    for (int it = 0; it < MT; ++it) {
      int row = srow + 32 * it;
      short8 s;
      s[0] = f2bf(fA[it].x); s[1] = f2bf(fA[it].y); s[2] = f2bf(fA[it].z); s[3] = f2bf(fA[it].w);
      s[4] = f2bf(fB[it].x); s[5] = f2bf(fB[it].y); s[6] = f2bf(fB[it].z); s[7] = f2bf(fB[it].w);
      *(short8*)(lds + swz(row * 128 + sc8 * 16)) = s;
    }
  };
  auto ISSUE_A = [&](int ks) {  // MODE 1: bf16 direct to LDS (TM/8 chunks of 1KB)
    const int k0 = ks * 64;
#pragma unroll
    for (int i = 0; i < TM / 32; ++i) {
      int ch = wid * (TM / 32) + i;
      int row = ch * 8 + rl;
      gload16((const short*)Ap + (size_t)(r0 + row) * 512 + k0 + scol * 8, lds + ch * 1024);
    }
  };
  auto ISSUE_B = [&](int ks) {  // both modes: 16 chunks of 1KB
    char* Bb = lds + TM * 128;
    const int k0 = ks * 64;
#pragma unroll
    for (int i = 0; i < 4; ++i) {
      int ch = wid * 4 + i;
      int row = ch * 8 + rl;
      gload16(Bp + (size_t)(n0 + row) * 512 + k0 + scol * 8, Bb + ch * 1024);
    }
  };

  f32x4 acc[MT][4] = {};

  if constexpr (MODE == 0) LOAD_A(0);

  for (int ks = 0; ks < 8; ++ks) {
    __syncthreads();                    // (a) all waves done reading the buffer
    if constexpr (MODE == 0) WRITE_A();
    else ISSUE_A(ks);
    ISSUE_B(ks);
    __syncthreads();                    // (b) ds_writes + gloads drained: tile ready
    if constexpr (MODE == 0) { if (ks < 7) LOAD_A(ks + 1); }   // in flight during compute

    const char* Bb = lds + TM * 128;
    short8 bfr[4][2];
#pragma unroll
    for (int nt = 0; nt < 4; ++nt)
#pragma unroll
      for (int kk = 0; kk < 2; ++kk) {
        int nr = wc * 64 + nt * 16 + c;
        bfr[nt][kk] = *(const short8*)(Bb + swz(nr * 128 + (g + 4 * kk) * 16));
      }
#pragma unroll
    for (int mt = 0; mt < MT; ++mt) {
      int row = wr * (TM / 2) + mt * 16 + c;
      short8 a0 = *(const short8*)(lds + swz(row * 128 + g * 16));
      short8 a1 = *(const short8*)(lds + swz(row * 128 + (g + 4) * 16));
#pragma unroll
      for (int nt = 0; nt < 4; ++nt) {
        acc[mt][nt] = MFMA16(a0, bfr[nt][0], acc[mt][nt]);
        acc[mt][nt] = MFMA16(a1, bfr[nt][1], acc[mt][nt]);
      }
    }
  }

  // ---- epilogue ----
  if constexpr (MODE == 0) {
    short* Ob = (short*)Op;
    const bool vtrans = (z == 2);
#pragma unroll
    for (int mt = 0; mt < MT; ++mt) {
      int rowb = r0 + wr * (TM / 2) + mt * 16 + g * 4;
#pragma unroll
      for (int nt = 0; nt < 4; ++nt) {
        int col = n0 + wc * 64 + nt * 16 + c;
        int hh = col >> 6, hs = col & 63;
#pragma unroll
        for (int r = 0; r < 4; ++r) {
          int row = rowb + r;
          int bb = row >> 11, nn = row & 2047;
          size_t off = vtrans ? ((((size_t)(bb * 8 + hh)) * 64 + hs) * 2048 + nn)
                              : ((((size_t)(bb * 8 + hh)) * 2048 + nn) * 64 + hs);
          Ob[off] = f2bf(acc[mt][nt][r]);
        }
      }
    }
  } else {
    float* Of = (float*)Op;
#pragma unroll
    for (int nt = 0; nt < 4; ++nt) {
      int col = n0 + wc * 64 + nt * 16 + c;
      float bv = bias[col];
#pragma unroll
      for (int mt = 0; mt < MT; ++mt) {
        int rowb = r0 + wr * (TM / 2) + mt * 16 + g * 4;
#pragma unroll
        for (int r = 0; r < 4; ++r)
          Of[(size_t)(rowb + r) * 512 + col] = acc[mt][nt][r] + bv;
      }
    }
  }
}

// ---------------- flash attention: UNCHANGED from round 6 (passing) ----------------

__global__ __launch_bounds__(256, 4) void attn64(const short* __restrict__ Qb,
                                                 const short* __restrict__ Kb,
                                                 const short* __restrict__ Vt,
                                                 short* __restrict__ MH) {
  __shared__ alignas(16) char lds[40960];
  const int flat = blockIdx.x;
  const int xcd = flat & 7, idx = flat >> 3;
  const int bh = xcd * 4 + (idx >> 5);
  const int qt = idx & 31;
  const int b = bh >> 3, h = bh & 7;

  const int tid = threadIdx.x, wid = tid >> 6, lane = tid & 63, g = lane >> 4, c = lane & 15;
  const short* Qp = Qb + ((size_t)bh * 2048 + qt * 64) * 64;
  const short* Kp = Kb + (size_t)bh * 2048 * 64;
  const short* Vp = Vt + (size_t)bh * 64 * 2048;

  const int rl = lane >> 3, cl = lane & 7, scol = cl ^ rl;

  auto ISSUE_KV = [&](int kvt, int buf) {
    char* Kd = lds + buf * 8192;
    char* Vd = lds + 16384 + buf * 8192;
#pragma unroll
    for (int i = 0; i < 2; ++i) {
      int ch = wid * 2 + i;
      int row = ch * 8 + rl;
      gload16(Kp + ((size_t)kvt * 64 + row) * 64 + scol * 8, Kd + ch * 1024);
      gload16(Vp + (size_t)row * 2048 + kvt * 64 + scol * 8, Vd + ch * 1024);
    }
  };

  short8 qf[2];
#pragma unroll
  for (int kk = 0; kk < 2; ++kk)
    qf[kk] = *(const short8*)(Qp + (wid * 16 + c) * 64 + g * 8 + kk * 32);

  f32x4 o[4] = {};
  float mrow[4], lrow[4];
#pragma unroll
  for (int r = 0; r < 4; ++r) { mrow[r] = -1e30f; lrow[r] = 0.f; }

  const int pbase = 32768 + wid * 2048;

  ISSUE_KV(0, 0);
  int cur = 0;

  for (int kvt = 0; kvt < 32; ++kvt) {
    __syncthreads();
    if (kvt < 31) ISSUE_KV(kvt + 1, cur ^ 1);
    const char* Kl = lds + cur * 8192;
    const char* Vl = lds + 16384 + cur * 8192;

    f32x4 s[4] = {};
#pragma unroll
    for (int t = 0; t < 4; ++t)
#pragma unroll
      for (int kk = 0; kk < 2; ++kk) {
        short8 kf = *(const short8*)(Kl + swz((t * 16 + c) * 128 + (g + 4 * kk) * 16));
        s[t] = MFMA16(qf[kk], kf, s[t]);
      }

#pragma unroll
    for (int r = 0; r < 4; ++r) {
      float vm = fmaxf(fmaxf(s[0][r], s[1][r]), fmaxf(s[2][r], s[3][r]));
      vm = fmaxf(vm, __shfl_xor(vm, 1));
      vm = fmaxf(vm, __shfl_xor(vm, 2));
      vm = fmaxf(vm, __shfl_xor(vm, 4));
      vm = fmaxf(vm, __shfl_xor(vm, 8));
      float mn = fmaxf(mrow[r], vm);
      float sc = __expf(mrow[r] - mn);
      float rs = 0.f;
#pragma unroll
      for (int t = 0; t < 4; ++t) {
        float p = __expf(s[t][r] - mn);
        s[t][r] = p;
        rs += p;
      }
      rs += __shfl_xor(rs, 1);
      rs += __shfl_xor(rs, 2);
      rs += __shfl_xor(rs, 4);
      rs += __shfl_xor(rs, 8);
      lrow[r] = lrow[r] * sc + rs;
      mrow[r] = mn;
#pragma unroll
      for (int t = 0; t < 4; ++t) o[t][r] *= sc;
    }

#pragma unroll
    for (int t = 0; t < 4; ++t)
#pragma unroll
      for (int r = 0; r < 4; ++r)
        *(short*)(lds + swz(pbase + (g * 4 + r) * 128 + (t * 16 + c) * 2)) = f2bf(s[t][r]);
    asm volatile("s_waitcnt lgkmcnt(0)" ::: "memory");

    short8 pa[2];
#pragma unroll
    for (int half = 0; half < 2; ++half)
      pa[half] = *(const short8*)(lds + swz(pbase + c * 128 + (g + 4 * half) * 16));
#pragma unroll
    for (int t = 0; t < 4; ++t)
#pragma unroll
      for (int half = 0; half < 2; ++half) {
        short8 vf = *(const short8*)(Vl + swz((t * 16 + c) * 128 + (g + 4 * half) * 16));
        o[t] = MFMA16(pa[half], vf, o[t]);
      }

    cur ^= 1;
  }

#pragma unroll
  for (int t = 0; t < 4; ++t)
#pragma unroll
    for (int r = 0; r < 4; ++r) {
      float val = o[t][r] / lrow[r];
      int qrow = qt * 64 + wid * 16 + g * 4 + r;
      int col = h * 64 + t * 16 + c;
      MH[((size_t)b * 2048 + qrow) * 512 + col] = f2bf(val);
    }
}

// ---------------- launcher ----------------

extern "C" void kernel_launch(void* const* d_in, const int* in_sizes, int n_in,
                              void* d_out, int out_size, void* d_ws, size_t ws_size,
                              hipStream_t stream) {
  const float* query = (const float*)d_in[0];
  const float* key = (const float*)d_in[1];
  const float* value = (const float*)d_in[2];
  const float* wq = (const float*)d_in[3];
  const float* wk = (const float*)d_in[4];
  const float* wv = (const float*)d_in[5];
  const float* wp = (const float*)d_in[6];
  const float* bias = (const float*)d_in[7];

  char* ws = (char*)d_ws;
  short* Wq_t = (short*)(ws + 0);
  short* Wk_t = (short*)(ws + 524288);
  short* Wv_t = (short*)(ws + 1048576);
  short* Wp_t = (short*)(ws + 1572864);
  short* Qb = (short*)(ws + 2097152);
  short* Kb = (short*)(ws + 2097152 + 8388608);
  short* Vb = (short*)(ws + 2097152 + 2 * (size_t)8388608);   // Vt[bh][hs][m]
  short* MH = (short*)(ws + 2097152 + 3 * (size_t)8388608);

  convT_qkv<<<dim3(64, 3), 256, 0, stream>>>(wq, wk, wv, Wq_t, Wk_t, Wv_t);
  convT_p<<<dim3(64), 256, 0, stream>>>(wp, Wp_t);
  gemmT<0, 128><<<dim3(64, 4, 3), 256, 0, stream>>>(query, key, value, Wq_t, Wk_t, Wv_t,
                                                    Qb, Kb, Vb, nullptr);
  attn64<<<dim3(1024), 256, 0, stream>>>(Qb, Kb, Vb, MH);
  gemmT<1, 64><<<dim3(128, 4, 1), 256, 0, stream>>>(MH, nullptr, nullptr, Wp_t, nullptr, nullptr,
                                                    d_out, nullptr, nullptr, bias);
}

// Round 11
// 208.747 us; speedup vs baseline: 1.2512x; 1.1637x over previous
//
#include <hip/hip_runtime.h>
#include <hip/hip_bf16.h>

// B=4, N=M=2048, D=512, H=8, HS=64, OUT=512
// convT_qkv : LDS-transpose W[H][D][HS] fp32 -> Wt[h*64+hs][k] bf16 (q scaled 1/8)
// convT_p   : LDS-transpose W[H][HS][OUT] fp32 -> Wt[out][h*64+hs] bf16
// gemmT<0,128>: X fp32 [8192,512] x Wt -> Q,K: [B*H][n][64]; V: [B*H][hs][m] (transposed)
// attn64    : flash attn, swapped QK^T + in-lane softmax, P via LDS b64 -> MH bf16
// gemmT<1,64> : MH x Wp_t + bias -> out fp32 [8192,512]

typedef __attribute__((ext_vector_type(8))) short short8;
typedef __attribute__((ext_vector_type(4))) float f32x4;

#define MFMA16(a, b, c) __builtin_amdgcn_mfma_f32_16x16x32_bf16(a, b, c, 0, 0, 0)

__device__ __forceinline__ short f2bf(float f) {
  unsigned u = __builtin_bit_cast(unsigned, f);
  u += 0x7FFF + ((u >> 16) & 1);   // RNE
  return (short)(u >> 16);
}

// XOR swizzle for 128B-row LDS tiles (bases must have bits 7-9 clear).
__device__ __forceinline__ unsigned swz(unsigned byte) {
  return byte ^ (((byte >> 7) & 7) << 4);
}

__device__ __forceinline__ void gload16(const void* g, void* l) {
  __builtin_amdgcn_global_load_lds((const __attribute__((address_space(1))) void*)g,
                                   (__attribute__((address_space(3))) void*)l, 16, 0, 0);
}

// ---------------- weight conversion: coalesced LDS transpose ----------------

__global__ void convT_qkv(const float* __restrict__ Wq, const float* __restrict__ Wk,
                          const float* __restrict__ Wv,
                          short* __restrict__ Oq, short* __restrict__ Ok,
                          short* __restrict__ Ov) {
  __shared__ short t[64][66];
  const int z = blockIdx.y;
  const float* W = (z == 0) ? Wq : (z == 1) ? Wk : Wv;
  short* O = (z == 0) ? Oq : (z == 1) ? Ok : Ov;
  const float scale = (z == 0) ? 0.125f : 1.0f;
  const int h = blockIdx.x >> 3, kb = blockIdx.x & 7;
  const int cl = threadIdx.x & 63, rw = threadIdx.x >> 6;
#pragma unroll
  for (int it = 0; it < 16; ++it) {
    int k = rw + it * 4;
    t[cl][k] = f2bf(W[((size_t)(h * 512) + kb * 64 + k) * 64 + cl] * scale);
  }
  __syncthreads();
#pragma unroll
  for (int it = 0; it < 16; ++it) {
    int hs = rw + it * 4;
    O[((size_t)(h * 64) + hs) * 512 + kb * 64 + cl] = t[hs][cl];
  }
}

__global__ void convT_p(const float* __restrict__ W, short* __restrict__ O) {
  __shared__ short t[64][66];
  const int kb = blockIdx.x & 7, nb = blockIdx.x >> 3;
  const int cl = threadIdx.x & 63, rw = threadIdx.x >> 6;
#pragma unroll
  for (int it = 0; it < 16; ++it) {
    int k = rw + it * 4;
    t[k][cl] = f2bf(W[(size_t)(kb * 64 + k) * 512 + nb * 64 + cl]);
  }
  __syncthreads();
#pragma unroll
  for (int it = 0; it < 16; ++it) {
    int n = rw + it * 4;
    O[(size_t)(nb * 64 + n) * 512 + kb * 64 + cl] = t[cl][n];
  }
}

// ---------------- GEMM: TMx128 tile, BK=64, single-buffer, 2 barriers/k-step ----------------
// (UNCHANGED from round 10, passing)

template <int MODE, int TM>
__global__ __launch_bounds__(256, 3) void gemmT(
    const void* __restrict__ A0, const void* __restrict__ A1, const void* __restrict__ A2,
    const short* __restrict__ B0, const short* __restrict__ B1, const short* __restrict__ B2,
    void* __restrict__ O0, void* __restrict__ O1, void* __restrict__ O2,
    const float* __restrict__ bias) {
  constexpr int MT = TM / 32;
  __shared__ alignas(16) char lds[TM * 128 + 16384];
  const int z = blockIdx.z;
  const void* Ap = (z == 0) ? A0 : (z == 1) ? A1 : A2;
  const short* Bp = (z == 0) ? B0 : (z == 1) ? B1 : B2;
  void* Op = (z == 0) ? O0 : (z == 1) ? O1 : O2;

  const int tid = threadIdx.x;
  const int r0 = blockIdx.x * TM;
  const int n0 = blockIdx.y * 128;
  const int wid = tid >> 6, lane = tid & 63, g = lane >> 4, c = lane & 15;
  const int wr = wid >> 1, wc = wid & 1;
  const int rl = lane >> 3, cl = lane & 7, scol = cl ^ rl;
  const int srow = tid >> 3, sc8 = tid & 7;

  float4 fA[MT], fB[MT];

  auto LOAD_A = [&](int ks) {
    const int k0 = ks * 64;
#pragma unroll
    for (int it = 0; it < MT; ++it) {
      int row = srow + 32 * it;
      const float* src = (const float*)Ap + (size_t)(r0 + row) * 512 + k0 + sc8 * 8;
      fA[it] = *(const float4*)(src);
      fB[it] = *(const float4*)(src + 4);
    }
  };
  auto WRITE_A = [&]() {
#pragma unroll
    for (int it = 0; it < MT; ++it) {
      int row = srow + 32 * it;
      short8 s;
      s[0] = f2bf(fA[it].x); s[1] = f2bf(fA[it].y); s[2] = f2bf(fA[it].z); s[3] = f2bf(fA[it].w);
      s[4] = f2bf(fB[it].x); s[5] = f2bf(fB[it].y); s[6] = f2bf(fB[it].z); s[7] = f2bf(fB[it].w);
      *(short8*)(lds + swz(row * 128 + sc8 * 16)) = s;
    }
  };
  auto ISSUE_A = [&](int ks) {
    const int k0 = ks * 64;
#pragma unroll
    for (int i = 0; i < TM / 32; ++i) {
      int ch = wid * (TM / 32) + i;
      int row = ch * 8 + rl;
      gload16((const short*)Ap + (size_t)(r0 + row) * 512 + k0 + scol * 8, lds + ch * 1024);
    }
  };
  auto ISSUE_B = [&](int ks) {
    char* Bb = lds + TM * 128;
    const int k0 = ks * 64;
#pragma unroll
    for (int i = 0; i < 4; ++i) {
      int ch = wid * 4 + i;
      int row = ch * 8 + rl;
      gload16(Bp + (size_t)(n0 + row) * 512 + k0 + scol * 8, Bb + ch * 1024);
    }
  };

  f32x4 acc[MT][4] = {};

  if constexpr (MODE == 0) LOAD_A(0);

  for (int ks = 0; ks < 8; ++ks) {
    __syncthreads();
    if constexpr (MODE == 0) WRITE_A();
    else ISSUE_A(ks);
    ISSUE_B(ks);
    __syncthreads();
    if constexpr (MODE == 0) { if (ks < 7) LOAD_A(ks + 1); }

    const char* Bb = lds + TM * 128;
    short8 bfr[4][2];
#pragma unroll
    for (int nt = 0; nt < 4; ++nt)
#pragma unroll
      for (int kk = 0; kk < 2; ++kk) {
        int nr = wc * 64 + nt * 16 + c;
        bfr[nt][kk] = *(const short8*)(Bb + swz(nr * 128 + (g + 4 * kk) * 16));
      }
#pragma unroll
    for (int mt = 0; mt < MT; ++mt) {
      int row = wr * (TM / 2) + mt * 16 + c;
      short8 a0 = *(const short8*)(lds + swz(row * 128 + g * 16));
      short8 a1 = *(const short8*)(lds + swz(row * 128 + (g + 4) * 16));
#pragma unroll
      for (int nt = 0; nt < 4; ++nt) {
        acc[mt][nt] = MFMA16(a0, bfr[nt][0], acc[mt][nt]);
        acc[mt][nt] = MFMA16(a1, bfr[nt][1], acc[mt][nt]);
      }
    }
  }

  if constexpr (MODE == 0) {
    short* Ob = (short*)Op;
    const bool vtrans = (z == 2);
#pragma unroll
    for (int mt = 0; mt < MT; ++mt) {
      int rowb = r0 + wr * (TM / 2) + mt * 16 + g * 4;
#pragma unroll
      for (int nt = 0; nt < 4; ++nt) {
        int col = n0 + wc * 64 + nt * 16 + c;
        int hh = col >> 6, hs = col & 63;
#pragma unroll
        for (int r = 0; r < 4; ++r) {
          int row = rowb + r;
          int bb = row >> 11, nn = row & 2047;
          size_t off = vtrans ? ((((size_t)(bb * 8 + hh)) * 64 + hs) * 2048 + nn)
                              : ((((size_t)(bb * 8 + hh)) * 2048 + nn) * 64 + hs);
          Ob[off] = f2bf(acc[mt][nt][r]);
        }
      }
    }
  } else {
    float* Of = (float*)Op;
#pragma unroll
    for (int nt = 0; nt < 4; ++nt) {
      int col = n0 + wc * 64 + nt * 16 + c;
      float bv = bias[col];
#pragma unroll
      for (int mt = 0; mt < MT; ++mt) {
        int rowb = r0 + wr * (TM / 2) + mt * 16 + g * 4;
#pragma unroll
        for (int r = 0; r < 4; ++r)
          Of[(size_t)(rowb + r) * 512 + col] = acc[mt][nt][r] + bv;
      }
    }
  }
}

// ---------------- flash attention: swapped QK^T, in-lane softmax, P via LDS b64 ----------------
// 256 thr = 4 waves, 16 q-rows/wave. LDS 40KB:
//   Kbuf[2] @0,@8192; Vbuf[2] (V^T) @16384,@24576; P per wave [16 q][64 kv] @32768+wid*2048.
// Swapped S^T = mfma(K, Q): lane (g,c) holds S[q=wid*16+c][kv=16t+4g+r] -> softmax in-lane
// (15 fmax + 2 shfl_xor). P packed to bf16 pairs, 4 ds_write_b64/lane; PV A-frag read
// byte-identical to the round-6/10 passing path.

__global__ __launch_bounds__(256, 4) void attn64(const short* __restrict__ Qb,
                                                 const short* __restrict__ Kb,
                                                 const short* __restrict__ Vt,
                                                 short* __restrict__ MH) {
  __shared__ alignas(16) char lds[40960];
  const int flat = blockIdx.x;
  const int xcd = flat & 7, idx = flat >> 3;
  const int bh = xcd * 4 + (idx >> 5);
  const int qt = idx & 31;
  const int b = bh >> 3, h = bh & 7;

  const int tid = threadIdx.x, wid = tid >> 6, lane = tid & 63, g = lane >> 4, c = lane & 15;
  const short* Qp = Qb + ((size_t)bh * 2048 + qt * 64) * 64;
  const short* Kp = Kb + (size_t)bh * 2048 * 64;
  const short* Vp = Vt + (size_t)bh * 64 * 2048;

  const int rl = lane >> 3, cl = lane & 7, scol = cl ^ rl;

  auto ISSUE_KV = [&](int kvt, int buf) {
    char* Kd = lds + buf * 8192;
    char* Vd = lds + 16384 + buf * 8192;
#pragma unroll
    for (int i = 0; i < 2; ++i) {
      int ch = wid * 2 + i;
      int row = ch * 8 + rl;
      gload16(Kp + ((size_t)kvt * 64 + row) * 64 + scol * 8, Kd + ch * 1024);
      gload16(Vp + (size_t)row * 2048 + kvt * 64 + scol * 8, Vd + ch * 1024);
    }
  };

  // Q fragment (B-operand of swapped QK^T): Q[q=wid*16+c][d=g*8+kk*32+j]
  short8 qf[2];
#pragma unroll
  for (int kk = 0; kk < 2; ++kk)
    qf[kk] = *(const short8*)(Qp + (wid * 16 + c) * 64 + g * 8 + kk * 32);

  f32x4 o[4] = {};
  float mrow = -1e30f, lrow = 0.f;   // per-lane softmax state for q = wid*16 + c

  const int pbase = 32768 + wid * 2048;

  ISSUE_KV(0, 0);
  int cur = 0;

  for (int kvt = 0; kvt < 32; ++kvt) {
    __syncthreads();
    if (kvt < 31) ISSUE_KV(kvt + 1, cur ^ 1);
    const char* Kl = lds + cur * 8192;
    const char* Vl = lds + 16384 + cur * 8192;

    // ---- S^T = mfma(K, Q): s[t][r] = S[q=wid*16+c][kv=16t+4g+r] ----
    f32x4 s[4] = {};
#pragma unroll
    for (int t = 0; t < 4; ++t)
#pragma unroll
      for (int kk = 0; kk < 2; ++kk) {
        short8 kf = *(const short8*)(Kl + swz((t * 16 + c) * 128 + (g + 4 * kk) * 16));
        s[t] = MFMA16(kf, qf[kk], s[t]);
      }

    // ---- online softmax: in-lane over 16 kv + cross-g reduce (2 shuffles) ----
    float vm = s[0][0];
#pragma unroll
    for (int t = 0; t < 4; ++t)
#pragma unroll
      for (int r = 0; r < 4; ++r) vm = fmaxf(vm, s[t][r]);
    vm = fmaxf(vm, __shfl_xor(vm, 16));
    vm = fmaxf(vm, __shfl_xor(vm, 32));
    if (__any(vm > mrow)) {           // exact defer: skip rescale when no row's max grew
      float mn = fmaxf(mrow, vm);
      float sc = __expf(mrow - mn);
      float s0 = __shfl(sc, 4 * g + 0);
      float s1 = __shfl(sc, 4 * g + 1);
      float s2 = __shfl(sc, 4 * g + 2);
      float s3 = __shfl(sc, 4 * g + 3);
#pragma unroll
      for (int t = 0; t < 4; ++t) {
        o[t][0] *= s0; o[t][1] *= s1; o[t][2] *= s2; o[t][3] *= s3;
      }
      lrow *= sc;
      mrow = mn;
    }
    float rs = 0.f;
#pragma unroll
    for (int t = 0; t < 4; ++t)
#pragma unroll
      for (int r = 0; r < 4; ++r) {
        float p = __expf(s[t][r] - mrow);
        s[t][r] = p;
        rs += p;
      }
    rs += __shfl_xor(rs, 16);
    rs += __shfl_xor(rs, 32);
    lrow += rs;

    // ---- P -> per-wave LDS: q-row = c, kv = 16t+4g+r; 4x ds_write_b64 ----
#pragma unroll
    for (int t = 0; t < 4; ++t) {
      unsigned lo = (unsigned short)f2bf(s[t][0]) |
                    ((unsigned)(unsigned short)f2bf(s[t][1]) << 16);
      unsigned hi = (unsigned short)f2bf(s[t][2]) |
                    ((unsigned)(unsigned short)f2bf(s[t][3]) << 16);
      unsigned long long pw = ((unsigned long long)hi << 32) | lo;
      *(unsigned long long*)(lds + swz(pbase + c * 128 + (16 * t + 4 * g) * 2)) = pw;
    }
    asm volatile("s_waitcnt lgkmcnt(0)" ::: "memory");

    // ---- PV: A-frag read identical to passing path ----
    short8 pa[2];
#pragma unroll
    for (int half = 0; half < 2; ++half)
      pa[half] = *(const short8*)(lds + swz(pbase + c * 128 + (g + 4 * half) * 16));
#pragma unroll
    for (int t = 0; t < 4; ++t)
#pragma unroll
      for (int half = 0; half < 2; ++half) {
        short8 vf = *(const short8*)(Vl + swz((t * 16 + c) * 128 + (g + 4 * half) * 16));
        o[t] = MFMA16(pa[half], vf, o[t]);
      }

    cur ^= 1;
  }

  // ---- epilogue: broadcast l per output row, normalize, write ----
  float l0 = __shfl(lrow, 4 * g + 0);
  float l1 = __shfl(lrow, 4 * g + 1);
  float l2 = __shfl(lrow, 4 * g + 2);
  float l3 = __shfl(lrow, 4 * g + 3);
  float inv0 = 1.f / l0, inv1 = 1.f / l1, inv2 = 1.f / l2, inv3 = 1.f / l3;
#pragma unroll
  for (int t = 0; t < 4; ++t) {
    int col = h * 64 + t * 16 + c;
    int rowb = qt * 64 + wid * 16 + g * 4;
    MH[((size_t)b * 2048 + rowb + 0) * 512 + col] = f2bf(o[t][0] * inv0);
    MH[((size_t)b * 2048 + rowb + 1) * 512 + col] = f2bf(o[t][1] * inv1);
    MH[((size_t)b * 2048 + rowb + 2) * 512 + col] = f2bf(o[t][2] * inv2);
    MH[((size_t)b * 2048 + rowb + 3) * 512 + col] = f2bf(o[t][3] * inv3);
  }
}

// ---------------- launcher ----------------

extern "C" void kernel_launch(void* const* d_in, const int* in_sizes, int n_in,
                              void* d_out, int out_size, void* d_ws, size_t ws_size,
                              hipStream_t stream) {
  const float* query = (const float*)d_in[0];
  const float* key = (const float*)d_in[1];
  const float* value = (const float*)d_in[2];
  const float* wq = (const float*)d_in[3];
  const float* wk = (const float*)d_in[4];
  const float* wv = (const float*)d_in[5];
  const float* wp = (const float*)d_in[6];
  const float* bias = (const float*)d_in[7];

  char* ws = (char*)d_ws;
  short* Wq_t = (short*)(ws + 0);
  short* Wk_t = (short*)(ws + 524288);
  short* Wv_t = (short*)(ws + 1048576);
  short* Wp_t = (short*)(ws + 1572864);
  short* Qb = (short*)(ws + 2097152);
  short* Kb = (short*)(ws + 2097152 + 8388608);
  short* Vb = (short*)(ws + 2097152 + 2 * (size_t)8388608);   // Vt[bh][hs][m]
  short* MH = (short*)(ws + 2097152 + 3 * (size_t)8388608);

  convT_qkv<<<dim3(64, 3), 256, 0, stream>>>(wq, wk, wv, Wq_t, Wk_t, Wv_t);
  convT_p<<<dim3(64), 256, 0, stream>>>(wp, Wp_t);
  gemmT<0, 128><<<dim3(64, 4, 3), 256, 0, stream>>>(query, key, value, Wq_t, Wk_t, Wv_t,
                                                    Qb, Kb, Vb, nullptr);
  attn64<<<dim3(1024), 256, 0, stream>>>(Qb, Kb, Vb, MH);
  gemmT<1, 64><<<dim3(128, 4, 1), 256, 0, stream>>>(MH, nullptr, nullptr, Wp_t, nullptr, nullptr,
                                                    d_out, nullptr, nullptr, bias);
}